// Round 9
// baseline (307.297 us; speedup 1.0000x reference)
//
#include <hip/hip_runtime.h>

typedef short  short8   __attribute__((ext_vector_type(8)));
typedef float  floatx4  __attribute__((ext_vector_type(4)));
typedef unsigned int uintx2 __attribute__((ext_vector_type(2)));

#define LOG2E_X2 2.8853900817779268f

// Inputs pre-scaled by 2*log2(e) (folded into W1/b1): tanh(a)=1-2/(exp2(y)+1).
__device__ __forceinline__ float tanh_pre(float y) {
    float e = __builtin_amdgcn_exp2f(y);
    return 1.0f - 2.0f * __builtin_amdgcn_rcpf(1.0f + e);
}

__device__ __forceinline__ unsigned short bf16rne(float f) {   // setup only
    unsigned u = __float_as_uint(f);
    u += 0x7FFFu + ((u >> 16) & 1u);
    return (unsigned short)(u >> 16);
}

// RNE-pack two f32 -> dword of 2 bf16 (lo=a, hi=b).
#if __has_builtin(__builtin_amdgcn_cvt_pk_bf16_f32)
__device__ __forceinline__ unsigned pk2(float a, float b) {
    auto r = __builtin_amdgcn_cvt_pk_bf16_f32(a, b);
    unsigned u; __builtin_memcpy(&u, &r, 4);
    return u;
}
#else
__device__ __forceinline__ unsigned pk2(float a, float b) {
    unsigned r;
    asm("v_cvt_pk_bf16_f32 %0, %1, %2" : "=v"(r) : "v"(a), "v"(b));
    return r;
}
#endif

// Unpack 4 bf16 (packed lo/hi per dword) -> floatx4, exact.
__device__ __forceinline__ floatx4 unpk4(uintx2 u) {
    floatx4 r;
    r[0] = __uint_as_float(u.x << 16);
    r[1] = __uint_as_float(u.x & 0xffff0000u);
    r[2] = __uint_as_float(u.y << 16);
    r[3] = __uint_as_float(u.y & 0xffff0000u);
    return r;
}

// Round 12: R6 base (252us best; R11 stagger removed as null) + STATIC-PHI
// registers. Atile cols 64..95 held Phi — constant across all 64 substeps —
// yet G1 re-read it from LDS as the kk=2 fragment every interval (2 of 6
// b128 reads = 33% of G1 read traffic). Now: Phi fragments loaded ONCE from
// global into xbP[4] (16 VGPR) at setup; kk=2 MFMA consumes registers; Phi
// LDS staging deleted. bf16rne == pk2's RNE and kk accumulation order is
// preserved -> bit-identical output (absmax 0.03125).
// Measured lessons kept: no mid-barrier rebalance (R8: serializes, 427us),
// no G2 tanh duplication (R10: +31% VALU cycles, 331us), no stagger (R11:
// null). LDS reads/CU-substep: 224 -> 192 b128.
__global__ __launch_bounds__(512, 4) void ode_mfma(
    const float* __restrict__ s_in,  const float* __restrict__ t_in,
    const float* __restrict__ phi_in,const float* __restrict__ bfr_in,
    const float* __restrict__ w1_in, const float* __restrict__ b1_in,
    const float* __restrict__ w2_in, const float* __restrict__ b2_in,
    float* __restrict__ out)
{
    const int tid  = threadIdx.x;
    const int w    = tid >> 6;         // wave 0..7
    const int lane = tid & 63;
    const int l15  = lane & 15;
    const int q    = lane >> 4;
    const int wg   = blockIdx.x;
    const int sb   = wg >> 5;
    const int n0   = (wg & 31) << 6;
    const int rowg0 = sb * 2048 + n0;

    __shared__ __align__(16) unsigned short Atile[64][104];  // cols 0..63 = x (cols 64+ unused)
    __shared__ __align__(16) unsigned short Hs[64][264];
    __shared__ float dls[8];

    if (tid < 8) dls[tid] = t_in[sb * 9 + tid + 1] - t_in[sb * 9 + tid];

// ---- G1 producer: stream row-tiles (RT0, RT0+1), this wave's 64 h-channels.
// kk=0,1 x-fragments from Atile (4 b128); kk=2 Phi fragment from registers.
#define DO_G1(RT0)                                                              \
    {                                                                           \
        floatx4 acc1[4][2];                                                     \
        {                                                                       \
            short8 xb[2];                                                       \
            _Pragma("unroll")                                                   \
            for (int r2 = 0; r2 < 2; ++r2)                                      \
                xb[r2] = *(const short8*)&Atile[(RT0 + r2) * 16 + l15][q * 8];  \
            _Pragma("unroll")                                                   \
            for (int ht = 0; ht < 4; ++ht)                                      \
                _Pragma("unroll")                                               \
                for (int r2 = 0; r2 < 2; ++r2)                                  \
                    acc1[ht][r2] = __builtin_amdgcn_mfma_f32_16x16x32_bf16(     \
                        w1f[ht][0], xb[r2], bbf[ht], 0, 0, 0);                  \
        }                                                                       \
        {                                                                       \
            short8 xb[2];                                                       \
            _Pragma("unroll")                                                   \
            for (int r2 = 0; r2 < 2; ++r2)                                      \
                xb[r2] = *(const short8*)&Atile[(RT0 + r2) * 16 + l15][32 + q * 8]; \
            _Pragma("unroll")                                                   \
            for (int ht = 0; ht < 4; ++ht)                                      \
                _Pragma("unroll")                                               \
                for (int r2 = 0; r2 < 2; ++r2)                                  \
                    acc1[ht][r2] = __builtin_amdgcn_mfma_f32_16x16x32_bf16(     \
                        w1f[ht][1], xb[r2], acc1[ht][r2], 0, 0, 0);             \
        }                                                                       \
        _Pragma("unroll")                                                       \
        for (int ht = 0; ht < 4; ++ht)                                          \
            _Pragma("unroll")                                                   \
            for (int r2 = 0; r2 < 2; ++r2)                                      \
                acc1[ht][r2] = __builtin_amdgcn_mfma_f32_16x16x32_bf16(         \
                    w1f[ht][2], xbP[RT0 + r2], acc1[ht][r2], 0, 0, 0);          \
        _Pragma("unroll")                                                       \
        for (int ht = 0; ht < 4; ++ht)                                          \
            _Pragma("unroll")                                                   \
            for (int r2 = 0; r2 < 2; ++r2) {                                    \
                uintx2 hp = { pk2(tanh_pre(acc1[ht][r2][0]), tanh_pre(acc1[ht][r2][1])), \
                              pk2(tanh_pre(acc1[ht][r2][2]), tanh_pre(acc1[ht][r2][3])) }; \
                *(uintx2*)&Hs[(RT0 + r2) * 16 + l15][hb0 + ht * 16 + q * 4] = hp; \
            }                                                                   \
    }

// ---- G2 consumer: stream SI, this wave's tile rt = SI*2+rt_rel, d cols
// dp..dp+32. Reads Hs (8 b128, each feeds 2 MFMA), RK4 epilogue, writes Atile.
#define DO_G2(SI)                                                               \
    {                                                                           \
        const int rt = (SI) * 2 + rt_rel;                                       \
        const unsigned short* hrow = &Hs[rt * 16 + l15][0];                     \
        floatx4 acc2a, acc2b;                                                   \
        {                                                                       \
            short8 hb = *(const short8*)&hrow[q * 8];                           \
            acc2a = __builtin_amdgcn_mfma_f32_16x16x32_bf16(                    \
                w2f[0][0], hb, unpk4(fpk[SI][0]), 0, 0, 0);                     \
            acc2b = __builtin_amdgcn_mfma_f32_16x16x32_bf16(                    \
                w2f[1][0], hb, unpk4(fpk[SI][1]), 0, 0, 0);                     \
        }                                                                       \
        _Pragma("unroll")                                                       \
        for (int kk = 1; kk < 8; ++kk) {                                        \
            short8 hb = *(const short8*)&hrow[kk * 32 + q * 8];                 \
            acc2a = __builtin_amdgcn_mfma_f32_16x16x32_bf16(                    \
                w2f[0][kk], hb, acc2a, 0, 0, 0);                                \
            acc2b = __builtin_amdgcn_mfma_f32_16x16x32_bf16(                    \
                w2f[1][kk], hb, acc2b, 0, 0, 0);                                \
        }                                                                       \
        _Pragma("unroll")                                                       \
        for (int h = 0; h < 2; ++h) {                                           \
            floatx4 kv = (h == 0 ? acc2a : acc2b) * dlt;                        \
            floatx4 xe;                                                         \
            if (sub == 0)      { kacc[SI][h] = kv;            xe = xv[SI][h] + 0.25f * kv; } \
            else if (sub == 1) { kacc[SI][h] += 2.0f * kv;    xe = xv[SI][h] + 0.25f * kv; } \
            else if (sub == 2) { kacc[SI][h] += 2.0f * kv;    xe = xv[SI][h] + 0.5f  * kv; } \
            else               { xv[SI][h] += (kacc[SI][h] + kv) * (1.0f / 12.0f); xe = xv[SI][h]; } \
            uintx2 px = { pk2(xe[0], xe[1]), pk2(xe[2], xe[3]) };               \
            *(uintx2*)&Atile[rt * 16 + l15][dp + h * 16 + q * 4] = px;          \
        }                                                                       \
        if (ii == 7) {                                                          \
            const size_t ob = (size_t)((sb * 8 + blk) * 2048 + n0 + rt * 16 + l15) * 64; \
            _Pragma("unroll")                                                   \
            for (int h = 0; h < 2; ++h)                                         \
                *(floatx4*)(out + ob + dp + h * 16 + q * 4) = xv[SI][h];        \
        }                                                                       \
    }

    if (w < 4) {
        // ================= G1 producer waves =================
        const int hb0 = w * 64;
        short8 w1f[4][3];
#pragma unroll
        for (int ht = 0; ht < 4; ++ht)
#pragma unroll
            for (int kk = 0; kk < 3; ++kk) {
                short8 f;
#pragma unroll
                for (int j = 0; j < 8; ++j) {
                    int k = kk * 32 + q * 8 + j;
                    int hc = hb0 + ht * 16 + l15;
                    f[j] = (short)bf16rne(w1_in[k * 256 + hc] * LOG2E_X2);
                }
                w1f[ht][kk] = f;
            }
        floatx4 bbf[4];
#pragma unroll
        for (int ht = 0; ht < 4; ++ht) {
            floatx4 v = *(const floatx4*)(b1_in + hb0 + ht * 16 + q * 4);
            bbf[ht] = v * LOG2E_X2;
        }
        // Static Phi fragments (kk=2 B-operand), one per row-tile. Same RNE
        // rounding as the old pk2 staging path -> identical MFMA inputs.
        short8 xbP[4];
#pragma unroll
        for (int t = 0; t < 4; ++t) {
            short8 f;
#pragma unroll
            for (int j = 0; j < 8; ++j)
                f[j] = (short)bf16rne(phi_in[(size_t)(rowg0 + t * 16 + l15) * 32 + q * 8 + j]);
            xbP[t] = f;
        }

        __syncthreads();                 // init barrier: Atile-x ready
        DO_G1(0)                         // prologue: HsA(0)
#pragma unroll 1
        for (int it = 0; it < 64; ++it) {
            __syncthreads();             // HsA(it)/AtileB(it) published
            DO_G1(2)                     // stream B, substep it
            __syncthreads();             // HsB(it)/AtileA(it+1) published
            if (it < 63) { DO_G1(0) }    // stream A, substep it+1
        }
    } else {
        // ================= G2 consumer waves =================
        const int g = w - 4;
        const int rt_rel = g >> 1;
        const int dp = (g & 1) * 32;
        short8 w2f[2][8];                // [d-half][kk]
#pragma unroll
        for (int h = 0; h < 2; ++h)
#pragma unroll
            for (int kk = 0; kk < 8; ++kk) {
                short8 f;
#pragma unroll
                for (int j = 0; j < 8; ++j) {
                    int k = kk * 32 + q * 8 + j;
                    f[j] = (short)bf16rne(w2_in[k * 64 + dp + h * 16 + l15]);
                }
                w2f[h][kk] = f;
            }

        floatx4 xv[2][2], kacc[2][2];
        uintx2 fpk[2][2];                // b2+bfr, bf16-packed C-seeds
#pragma unroll
        for (int si = 0; si < 2; ++si) {
            const int rt = si * 2 + rt_rel;
            const int rg = rowg0 + rt * 16 + l15;
#pragma unroll
            for (int h = 0; h < 2; ++h) {
                const int dh = dp + h * 16 + q * 4;
                xv[si][h] = *(const floatx4*)(s_in + rg * 64 + dh);
                floatx4 fb = *(const floatx4*)(b2_in + dh)
                           + *(const floatx4*)(bfr_in + rg * 64 + dh);
                fpk[si][h] = (uintx2){ pk2(fb[0], fb[1]), pk2(fb[2], fb[3]) };
                uintx2 px = { pk2(xv[si][h][0], xv[si][h][1]),
                              pk2(xv[si][h][2], xv[si][h][3]) };
                *(uintx2*)&Atile[rt * 16 + l15][dh] = px;
            }
        }

        __syncthreads();                 // init barrier: Atile-x ready
#pragma unroll 1
        for (int blk = 0; blk < 8; ++blk) {
            const float dlt = dls[blk];
#pragma unroll 1
            for (int ii = 0; ii < 8; ++ii) {
                const int sub = ii & 3;
                __syncthreads();         // HsA(i)/AtileB(i) published
                DO_G2(0)                 // stream A: GEMM2 + RK4 epilogue
                __syncthreads();         // HsB(i)/AtileA(i+1) published
                DO_G2(1)                 // stream B: GEMM2 + RK4 epilogue
            }
        }
    }
#undef DO_G1
#undef DO_G2
}

extern "C" void kernel_launch(void* const* d_in, const int* in_sizes, int n_in,
                              void* d_out, int out_size, void* d_ws, size_t ws_size,
                              hipStream_t stream) {
    const float* s_in  = (const float*)d_in[0];
    const float* t_in  = (const float*)d_in[1];
    const float* phi   = (const float*)d_in[2];
    const float* bfr   = (const float*)d_in[3];
    const float* w1    = (const float*)d_in[4];
    const float* b1    = (const float*)d_in[5];
    const float* w2    = (const float*)d_in[6];
    const float* b2    = (const float*)d_in[7];
    ode_mfma<<<512, 512, 0, stream>>>(s_in, t_in, phi, bfr, w1, b1, w2, b2, (float*)d_out);
}